// Round 6
// baseline (499.323 us; speedup 1.0000x reference)
//
#include <hip/hip_runtime.h>
#include <math.h>

// Problem constants
#define NB   8
#define CCH  256
#define PPX  2304            // 48*48
#define CPb  (CCH*PPX)       // per-batch C*P = 589824
#define NTOT (NB*CPb)        // 4718592
#define PSQ  (PPX*PPX)       // 5308416
#define PADIMG 2500          // 50*50 padded image

typedef short short8_t __attribute__((ext_vector_type(8)));
typedef float f4_t __attribute__((ext_vector_type(4)));

__device__ __forceinline__ float relu_(float x){ return x > 0.f ? x : 0.f; }

__device__ __forceinline__ unsigned short f2bf(float f) {
  unsigned int u = __builtin_bit_cast(unsigned int, f);
  u += 0x7fffu + ((u >> 16) & 1u);
  return (unsigned short)(u >> 16);
}
__device__ __forceinline__ float bf2f(unsigned short h) {
  unsigned int u = ((unsigned int)h) << 16;
  return __builtin_bit_cast(float, u);
}
__device__ __forceinline__ unsigned int pack2(float a, float b) {
  return (unsigned int)f2bf(a) | ((unsigned int)f2bf(b) << 16);
}

// async global -> LDS, 16B per lane, wave-uniform LDS base (lane spreads x16B)
__device__ __forceinline__ void gll16(const void* g, void* l) {
  __builtin_amdgcn_global_load_lds(
      (const __attribute__((address_space(1))) unsigned int*)g,
      (__attribute__((address_space(3))) unsigned int*)l, 16, 0, 0);
}

// ---------------------------------------------------------------------------
// small casts / repacks
// ---------------------------------------------------------------------------
__global__ __launch_bounds__(256) void castw(
    const float* __restrict__ w, unsigned short* __restrict__ o, int n)
{
  const int i = blockIdx.x * 256 + threadIdx.x;
  if (i < n) o[i] = f2bf(w[i]);
}

__global__ __launch_bounds__(256) void repack_w(
    const float* __restrict__ w, unsigned short* __restrict__ wr, int Cin)
{
  const int idx = blockIdx.x * 256 + threadIdx.x;
  const int total = 9 * 256 * Cin;
  if (idx >= total) return;
  const int c = idx % Cin;
  const int rest = idx / Cin;
  const int o = rest % 256;
  const int tap = rest / 256;
  wr[idx] = f2bf(w[((size_t)o * Cin + c) * 9 + tap]);
}

// ftr [b][c][p] fp32 -> x_t [b][p][c] bf16
__global__ __launch_bounds__(256) void transpose_cast(
    const float* __restrict__ ftr, unsigned short* __restrict__ xt)
{
  const int p0 = blockIdx.x * 64, c0 = blockIdx.y * 64, b = blockIdx.z;
  const int t = threadIdx.x;
  __shared__ unsigned short T[64][72];
  #pragma unroll
  for (int pass = 0; pass < 4; pass++) {
    const int cr = pass * 16 + (t >> 4);
    const int pc = (t & 15) * 4;
    float4 v = *(const float4*)&ftr[((size_t)(b * 256 + c0 + cr)) * PPX + p0 + pc];
    T[pc + 0][cr] = f2bf(v.x); T[pc + 1][cr] = f2bf(v.y);
    T[pc + 2][cr] = f2bf(v.z); T[pc + 3][cr] = f2bf(v.w);
  }
  __syncthreads();
  #pragma unroll
  for (int pass = 0; pass < 2; pass++) {
    const int pr = pass * 32 + (t >> 3);
    const int cc = (t & 7) * 8;
    *(uint4*)&xt[((size_t)(b * PPX + p0 + pr)) * 256 + c0 + cc] = *(const uint4*)&T[pr][cc];
  }
}

// ---------------------------------------------------------------------------
// Generic bf16 MFMA GEMM: O[n][m] = sum_k A[m][k]*B[n][k]
// Tile 128x128, 4 waves. Double-buffered async staging, 1 barrier per k-step.
// EPI: 0 none, 1 bias on m, 2 bias on n, 3 pv-epilogue (delta*acc+ftr -> attn_p)
// ---------------------------------------------------------------------------
template<int EPI>
__global__ __launch_bounds__(256) void gemm_nt(
    const unsigned short* __restrict__ A, long Ab,
    const unsigned short* __restrict__ B, long Bb, int K,
    unsigned short* __restrict__ O, long Ob, int ldo,
    const float* __restrict__ bias,
    const float* __restrict__ ftr, const float* __restrict__ delta, int bstart)
{
  const int t = threadIdx.x;
  const int ln = t & 63;
  const int wid = t >> 6;
  const int wm = (wid & 1) * 64, wn = (wid >> 1) * 64;
  const int lm = ln & 15, lg = ln >> 4;
  const int m0 = blockIdx.x * 128, n0 = blockIdx.y * 128;
  const long bz = blockIdx.z;
  const unsigned short* Ap = A + bz * Ab;
  const unsigned short* Bp = B + bz * Bb;

  __shared__ __align__(16) unsigned short As[2][128 * 32];
  __shared__ __align__(16) unsigned short Bs[2][128 * 32];

  const int sR = ln >> 2, sP = ln & 3;
  const int fbase = lm * 32 + (((lg + (lm >> 2)) & 3) * 8);

  f4_t acc[4][4];
  #pragma unroll
  for (int i = 0; i < 4; i++)
    #pragma unroll
    for (int j = 0; j < 4; j++) acc[i][j] = (f4_t){0.f, 0.f, 0.f, 0.f};

  const int S = K / 32;

  // prologue: stage slice 0 into buffer 0
  #pragma unroll
  for (int i = wid; i < 8; i += 4) {
    const int R = i * 16 + sR;
    const int l = (sP - (R >> 2)) & 3;
    gll16(Ap + (size_t)(m0 + R) * K + l * 8, &As[0][i * 512]);
    gll16(Bp + (size_t)(n0 + R) * K + l * 8, &Bs[0][i * 512]);
  }

  for (int s = 0; s < S; s++) {
    __syncthreads();   // slice s landed; buf[(s+1)&1] readers done
    if (s + 1 < S) {
      const int kk = (s + 1) * 32;
      #pragma unroll
      for (int i = wid; i < 8; i += 4) {
        const int R = i * 16 + sR;
        const int l = (sP - (R >> 2)) & 3;
        gll16(Ap + (size_t)(m0 + R) * K + kk + l * 8, &As[(s + 1) & 1][i * 512]);
        gll16(Bp + (size_t)(n0 + R) * K + kk + l * 8, &Bs[(s + 1) & 1][i * 512]);
      }
    }
    const unsigned short* Asb = As[s & 1];
    const unsigned short* Bsb = Bs[s & 1];
    short8_t a[4], b[4];
    #pragma unroll
    for (int ti = 0; ti < 4; ti++)
      a[ti] = *(const short8_t*)(Asb + (wm + ti * 16) * 32 + fbase);
    #pragma unroll
    for (int tj = 0; tj < 4; tj++)
      b[tj] = *(const short8_t*)(Bsb + (wn + tj * 16) * 32 + fbase);
    #pragma unroll
    for (int ti = 0; ti < 4; ti++)
      #pragma unroll
      for (int tj = 0; tj < 4; tj++)
        acc[ti][tj] = __builtin_amdgcn_mfma_f32_16x16x32_bf16(
            a[ti], b[tj], acc[ti][tj], 0, 0, 0);
  }

  if (EPI == 3) {
    const int b = bstart + (int)bz;
    const float d0 = delta[0];
    #pragma unroll
    for (int ti = 0; ti < 4; ti++) {
      const int mb = m0 + wm + ti * 16 + (lg << 2);   // channel c
      #pragma unroll
      for (int tj = 0; tj < 4; tj++) {
        const int n = n0 + wn + tj * 16 + lm;          // pixel j
        const int y = n / 48, x = n - (n / 48) * 48;
        const size_t pp = (size_t)(y + 1) * 50 + (x + 1);
        float vr[4];
        #pragma unroll
        for (int r = 0; r < 4; r++)
          vr[r] = d0 * acc[ti][tj][r] + ftr[((size_t)(b * 256 + mb + r)) * PPX + n];
        uint2 o;
        o.x = pack2(vr[0], vr[1]);
        o.y = pack2(vr[2], vr[3]);
        *(uint2*)(O + ((size_t)b * PADIMG + pp) * 256 + mb) = o;
      }
    }
  } else {
    #pragma unroll
    for (int ti = 0; ti < 4; ti++) {
      const int mb = m0 + wm + ti * 16 + (lg << 2);
      #pragma unroll
      for (int tj = 0; tj < 4; tj++) {
        const int n = n0 + wn + tj * 16 + lm;
        float add0 = 0.f, add1 = 0.f, add2 = 0.f, add3 = 0.f;
        if (EPI == 1) { add0 = bias[mb]; add1 = bias[mb+1]; add2 = bias[mb+2]; add3 = bias[mb+3]; }
        if (EPI == 2) { add0 = add1 = add2 = add3 = bias[n]; }
        uint2 o;
        o.x = pack2(acc[ti][tj][0] + add0, acc[ti][tj][1] + add1);
        o.y = pack2(acc[ti][tj][2] + add2, acc[ti][tj][3] + add3);
        *(uint2*)(O + bz * Ob + (size_t)n * ldo + mb) = o;
      }
    }
  }
}

// ---------------------------------------------------------------------------
// Row softmax of St IN PLACE: row j: W[i] = exp(s-mx)/sum  (bf16 out)
// ---------------------------------------------------------------------------
__global__ __launch_bounds__(256) void rowstats(
    unsigned short* __restrict__ St, long sstride)
{
  const int j = blockIdx.x, bb = blockIdx.y;
  unsigned short* row = St + (long)bb * sstride + (size_t)j * PPX;
  const int t = threadIdx.x;

  float v[16];
  int nv = 0;
  float m = -1e30f;
  for (int ch = t; ch < 288; ch += 256) {
    const uint4 d = *(const uint4*)(row + ch * 8);
    const unsigned int* dp = (const unsigned int*)&d;
    #pragma unroll
    for (int q = 0; q < 4; q++) {
      v[nv]     = bf2f((unsigned short)(dp[q] & 0xffffu));
      v[nv + 1] = bf2f((unsigned short)(dp[q] >> 16));
      m = fmaxf(m, fmaxf(v[nv], v[nv + 1]));
      nv += 2;
    }
  }
  __shared__ float red[256];
  red[t] = m; __syncthreads();
  for (int s = 128; s > 0; s >>= 1) {
    if (t < s) red[t] = fmaxf(red[t], red[t + s]);
    __syncthreads();
  }
  m = red[0]; __syncthreads();
  float sum = 0.f;
  for (int u = 0; u < nv; u++) { v[u] = expf(v[u] - m); sum += v[u]; }
  red[t] = sum; __syncthreads();
  for (int s = 128; s > 0; s >>= 1) {
    if (t < s) red[t] += red[t + s];
    __syncthreads();
  }
  const float inv = 1.f / red[0];
  int u = 0;
  for (int ch = t; ch < 288; ch += 256) {
    unsigned int res[4];
    #pragma unroll
    for (int q = 0; q < 4; q++) {
      res[q] = pack2(v[u] * inv, v[u + 1] * inv);
      u += 2;
    }
    *(uint4*)(row + ch * 8) = *(const uint4*)res;
  }
}

// ---------------------------------------------------------------------------
// Conv3x3 + BN + ReLU, MFMA bf16, [pos][chan] activations.
// Block: 256 thr (4 waves), tile 64 Cout x 288 px; wave = 32 Cout x 144 px.
// Weights: direct global->VGPR A-fragments (no LDS).
// Activations: LDS double-buffered (2x25.6 KB), 1 barrier per 32-chan slice,
// B(s+1) prefetch issued after the barrier and drained by the next one.
// ---------------------------------------------------------------------------
template<bool OUT_BF16>
__global__ __launch_bounds__(256) void conv_mfma(
    const unsigned short* __restrict__ act_p, int Cin,
    const unsigned short* __restrict__ wr,
    const float* __restrict__ gamma, const float* __restrict__ beta,
    const float* __restrict__ mean,  const float* __restrict__ var,
    void* __restrict__ outv)
{
  const int t  = threadIdx.x;
  const int wid = t >> 6;
  const int ln = t & 63;
  const int lm = ln & 15;
  const int lg = ln >> 4;
  const int wm  = wid & 1;      // Cout half (32)
  const int wpx = wid >> 1;     // pixel half (144)

  const int bx = blockIdx.x;    // 64 = 8 images * 8 pixel-tiles(288)
  const int bb = bx >> 3;
  const int p0 = (bx & 7) * 288;
  const int m0 = blockIdx.y * 64;

  __shared__ __align__(16) unsigned short Bs[2][400 * 32];   // 51.2 KB

  const int qbase = p0 + 2 * (p0 / 48);   // q(p0) - 51; rows qbase..qbase+399 all in [0,2499]
  int qoff[9];
  #pragma unroll
  for (int tj = 0; tj < 9; tj++) {
    const int dp = wpx * 144 + tj * 16 + lm;       // 0..287
    qoff[tj] = dp + 2 * (dp / 48) + 51;
  }
  const int sR = ln >> 2, sP = ln & 3;

  f4_t acc[2][9];
  #pragma unroll
  for (int i = 0; i < 2; i++)
    #pragma unroll
    for (int j = 0; j < 9; j++) acc[i][j] = (f4_t){0.f, 0.f, 0.f, 0.f};

  const unsigned short* gb = act_p + (size_t)bb * PADIMG * Cin;

  // prologue: stage slice 0
  for (int i = wid; i < 25; i += 4) {
    const int R = i * 16 + sR;
    const int l = (sP - (R >> 2)) & 3;
    gll16(gb + (size_t)(qbase + R) * Cin + l * 8, &Bs[0][i * 512]);
  }

  const int S = Cin / 32;
  for (int s = 0; s < S; s++) {
    __syncthreads();            // slice s landed; buf[(s+1)&1] readers done
    const int c0 = s * 32;
    // A-fragments: direct global loads (issued BEFORE the B-prefetch so
    // waiting on A does not drain it)
    short8_t a[2][9];
    #pragma unroll
    for (int tap = 0; tap < 9; tap++)
      #pragma unroll
      for (int ti = 0; ti < 2; ti++)
        a[ti][tap] = *(const short8_t*)(wr +
            ((size_t)(tap * 256 + m0 + wm * 32 + ti * 16 + lm)) * Cin + c0 + lg * 8);
    if (s + 1 < S) {
      const int cn = c0 + 32;
      for (int i = wid; i < 25; i += 4) {
        const int R = i * 16 + sR;
        const int l = (sP - (R >> 2)) & 3;
        gll16(gb + (size_t)(qbase + R) * Cin + cn + l * 8, &Bs[(s + 1) & 1][i * 512]);
      }
    }
    const unsigned short* Bsb = Bs[s & 1];
    #pragma unroll
    for (int ky = 0; ky < 3; ky++) {
      #pragma unroll
      for (int kx = 0; kx < 3; kx++) {
        const int off = (ky - 1) * 50 + (kx - 1);
        const int tap = ky * 3 + kx;
        #pragma unroll
        for (int tj = 0; tj < 9; tj++) {
          const int R = qoff[tj] + off;
          const int slot = (lg + (R >> 2)) & 3;
          const short8_t bfr = *(const short8_t*)(Bsb + R * 32 + slot * 8);
          acc[0][tj] = __builtin_amdgcn_mfma_f32_16x16x32_bf16(
              a[0][tap], bfr, acc[0][tj], 0, 0, 0);
          acc[1][tj] = __builtin_amdgcn_mfma_f32_16x16x32_bf16(
              a[1][tap], bfr, acc[1][tj], 0, 0, 0);
        }
      }
    }
  }

  // ---- epilogue: BN + ReLU ----
  #pragma unroll
  for (int ti = 0; ti < 2; ti++) {
    const int m = m0 + wm * 32 + ti * 16 + (lg << 2);
    float inv[4], add[4];
    #pragma unroll
    for (int r = 0; r < 4; r++) {
      inv[r] = gamma[m + r] * rsqrtf(var[m + r] + 1e-5f);
      add[r] = beta[m + r] - mean[m + r] * inv[r];
    }
    #pragma unroll
    for (int tj = 0; tj < 9; tj++) {
      const int p = p0 + wpx * 144 + tj * 16 + lm;
      float vr[4];
      #pragma unroll
      for (int r = 0; r < 4; r++)
        vr[r] = relu_(acc[ti][tj][r] * inv[r] + add[r]);
      if (OUT_BF16) {
        uint2 o;
        o.x = pack2(vr[0], vr[1]);
        o.y = pack2(vr[2], vr[3]);
        *(uint2*)((unsigned short*)outv + ((size_t)(bb * PPX + p)) * 256 + m) = o;
      } else {
        #pragma unroll
        for (int r = 0; r < 4; r++)
          ((float*)outv)[((size_t)(bb * 256 + m + r)) * PPX + p] = vr[r];
      }
    }
  }
}

// ---------------------------------------------------------------------------
// pool3(avg/max of xt bf16) * sigmoid(act1) -> padded bf16 cat [pos][512]
// ---------------------------------------------------------------------------
__global__ __launch_bounds__(256) void pool_gate_cat(
    const unsigned short* __restrict__ xt, const unsigned short* __restrict__ act1b,
    unsigned short* __restrict__ cat_p)
{
  const int idx = blockIdx.x * 256 + threadIdx.x;   // < NTOT
  const int c = idx & 255;
  const int rest = idx >> 8;
  const int p = rest % PPX;
  const int b = rest / PPX;
  const int y = p / 48, x = p - (p / 48) * 48;
  const unsigned short* base = xt + ((size_t)b * PPX) * 256 + c;
  float s = 0.f, mxv = -1e30f;
  #pragma unroll
  for (int dy = -1; dy <= 1; dy++) {
    const int yy = y + dy;
    if (yy < 0 || yy >= 48) continue;
    #pragma unroll
    for (int dx = -1; dx <= 1; dx++) {
      const int xx = x + dx;
      if (xx < 0 || xx >= 48) continue;
      const float f = bf2f(base[(size_t)(yy * 48 + xx) * 256]);
      s += f; mxv = fmaxf(mxv, f);
    }
  }
  const float g = bf2f(act1b[(size_t)idx]);
  const float gate = 1.f / (1.f + expf(-g));
  const size_t pp = (size_t)(y + 1) * 50 + (x + 1);
  unsigned short* crow = cat_p + ((size_t)b * PADIMG + pp) * 512;
  crow[c]       = f2bf(mxv * gate);
  crow[c + 256] = f2bf(s * (1.f / 9.f) * gate);
}

// ---------------------------------------------------------------------------
extern "C" void kernel_launch(void* const* d_in, const int* in_sizes, int n_in,
                              void* d_out, int out_size, void* d_ws, size_t ws_size,
                              hipStream_t stream)
{
  const float* ftr  = (const float*)d_in[0];
  const float* wq   = (const float*)d_in[1];
  const float* bq   = (const float*)d_in[2];
  const float* wk   = (const float*)d_in[3];
  const float* bk   = (const float*)d_in[4];
  const float* wv   = (const float*)d_in[5];
  const float* bv   = (const float*)d_in[6];
  const float* delta= (const float*)d_in[7];
  const float* w1   = (const float*)d_in[8];
  const float* g1   = (const float*)d_in[9];
  const float* b1   = (const float*)d_in[10];
  const float* m1   = (const float*)d_in[11];
  const float* v1   = (const float*)d_in[12];
  const float* w2   = (const float*)d_in[13];
  const float* g2   = (const float*)d_in[14];
  const float* b2   = (const float*)d_in[15];
  const float* m2   = (const float*)d_in[16];
  const float* v2   = (const float*)d_in[17];
  float* out = (float*)d_out;

  // ---- workspace layout (shorts) ----
  const size_t XT = (size_t)NTOT;
  unsigned short* base = (unsigned short*)d_ws;
  unsigned short* xt   = base;
  unsigned short* qt   = xt  + XT;
  unsigned short* kt   = qt  + XT;
  unsigned short* vbuf = kt  + XT;
  unsigned short* wqb  = vbuf + XT;
  unsigned short* wkb  = wqb + 65536;
  unsigned short* wvb  = wkb + 65536;
  unsigned short* wr1  = wvb + 65536;
  unsigned short* wr2  = wr1 + (size_t)9 * 256 * 256;
  unsigned short* attn_p = wr2 + (size_t)9 * 256 * 512;        // [b][2500][256]
  unsigned short* act1b  = attn_p + (size_t)NB * PADIMG * 256; // [b][2304][256]
  unsigned short* cat_p  = act1b + XT;                         // [b][2500][512]
  unsigned short* St     = cat_p + (size_t)NB * PADIMG * 512;

  const size_t head_bytes = (size_t)((char*)St - (char*)base);
  const bool modeA = ws_size >= head_bytes + (size_t)NB * PSQ * 2;

  const size_t ATTN_P_SH = (size_t)NB * PADIMG * 256;
  const size_t CAT_P_SH  = (size_t)NB * PADIMG * 512;

  // ---- weight preps ----
  castw<<<dim3(256), 256, 0, stream>>>(wq, wqb, 65536);
  castw<<<dim3(256), 256, 0, stream>>>(wk, wkb, 65536);
  castw<<<dim3(256), 256, 0, stream>>>(wv, wvb, 65536);
  repack_w<<<dim3((9 * 256 * 256 + 255) / 256), 256, 0, stream>>>(w1, wr1, 256);
  repack_w<<<dim3((9 * 256 * 512 + 255) / 256), 256, 0, stream>>>(w2, wr2, 512);

  // ---- x transpose ----
  transpose_cast<<<dim3(36, 4, 8), 256, 0, stream>>>(ftr, xt);

  // ---- QKV ----
  gemm_nt<1><<<dim3(2, 18, 8), 256, 0, stream>>>(
      wqb, 0L, xt, (long)CPb, 256, qt, (long)CPb, 256, bq, nullptr, nullptr, 0);
  gemm_nt<1><<<dim3(2, 18, 8), 256, 0, stream>>>(
      wkb, 0L, xt, (long)CPb, 256, kt, (long)CPb, 256, bk, nullptr, nullptr, 0);
  gemm_nt<2><<<dim3(18, 2, 8), 256, 0, stream>>>(
      xt, (long)CPb, wvb, 0L, 256, vbuf, (long)CPb, PPX, bv, nullptr, nullptr, 0);

  hipMemsetAsync(attn_p, 0, ATTN_P_SH * 2, stream);

  if (modeA) {
    gemm_nt<0><<<dim3(18, 18, 8), 256, 0, stream>>>(
        qt, (long)CPb, kt, (long)CPb, 256, St, (long)PSQ, PPX, nullptr, nullptr, nullptr, 0);
    rowstats<<<dim3(PPX, 8), 256, 0, stream>>>(St, (long)PSQ);
    gemm_nt<3><<<dim3(2, 18, 8), 256, 0, stream>>>(
        vbuf, (long)CPb, St, (long)PSQ, PPX, attn_p, 0L, 0, nullptr, ftr, delta, 0);
  } else {
    for (int b = 0; b < NB; b++) {
      gemm_nt<0><<<dim3(18, 18, 1), 256, 0, stream>>>(
          qt + (size_t)b * CPb, 0L, kt + (size_t)b * CPb, 0L, 256,
          St, 0L, PPX, nullptr, nullptr, nullptr, 0);
      rowstats<<<dim3(PPX, 1), 256, 0, stream>>>(St, 0L);
      gemm_nt<3><<<dim3(2, 18, 1), 256, 0, stream>>>(
          vbuf + (size_t)b * CPb, 0L, St, 0L, PPX, attn_p, 0L, 0, nullptr, ftr, delta, b);
    }
  }

  // ---- conv1 + BN + ReLU -> bf16 act1b [p][c] ----
  conv_mfma<true><<<dim3(64, 4), 256, 0, stream>>>(
      attn_p, 256, wr1, g1, b1, m1, v1, (void*)act1b);

  // ---- pool + gate + concat -> padded bf16 cat [pos][512] ----
  hipMemsetAsync(cat_p, 0, CAT_P_SH * 2, stream);
  pool_gate_cat<<<dim3(NTOT / 256), 256, 0, stream>>>(xt, act1b, cat_p);

  // ---- conv2 + BN + ReLU -> fp32 out ----
  conv_mfma<false><<<dim3(64, 4), 256, 0, stream>>>(
      cat_p, 512, wr2, g2, b2, m2, v2, (void*)out);
}